// Round 1
// baseline (2262.262 us; speedup 1.0000x reference)
//
#include <hip/hip_runtime.h>
#include <cstddef>

#define EPS 1e-5f
#define NNODE 30000
#define NEDGE 360000
#define NFEAT 92
#define EF 41
#define D 64
#define LAY 3
#define FCW 128
#define NG 64

typedef unsigned short bf16;
typedef __attribute__((ext_vector_type(8))) short short8v;   // 8 bf16 (4 VGPRs) — MFMA A/B frag
typedef __attribute__((ext_vector_type(4))) float float4v;   // MFMA C/D frag

__device__ __forceinline__ float b2f(bf16 u) { return __uint_as_float(((unsigned)u) << 16); }
__device__ __forceinline__ bf16 f2b(float f) {
    unsigned u = __float_as_uint(f);
    unsigned r = (u + 0x7FFFu + ((u >> 16) & 1u)) >> 16;
    return (bf16)r;
}
__device__ __forceinline__ float softplusf(float x) {
    return fmaxf(x, 0.0f) + log1pf(expf(-fabsf(x)));
}
// packed (gate,scr) dword helpers: low u16 = gate, high u16 = scr
__device__ __forceinline__ float lof(unsigned u) { return __uint_as_float(u << 16); }
__device__ __forceinline__ float hif(unsigned u) { return __uint_as_float(u & 0xffff0000u); }

// ---------------- embedding matmul: pre = X[N,92] @ W[92,64] + b, accumulate col stats
#define EMB_RPB 64
__global__ __launch_bounds__(256) void k_emb_mm(const float* __restrict__ X, const float* __restrict__ W,
                                                const float* __restrict__ bias, float* __restrict__ pre,
                                                float* __restrict__ stats, int N) {
    __shared__ float xs[EMB_RPB][NFEAT];   // 23.5 KB; row stride 368B = 16B aligned
    __shared__ float red[4][2][64];
    int tid = threadIdx.x;
    int lane = tid & 63, wid = tid >> 6;
    int r0 = blockIdx.x * EMB_RPB;
    float w[NFEAT];
#pragma unroll
    for (int k = 0; k < NFEAT; k++) w[k] = W[k * D + lane];
    float bcol = bias[lane];
    for (int i = tid; i < EMB_RPB * (NFEAT / 4); i += 256) {
        int rr = i / (NFEAT / 4), kk = i - rr * (NFEAT / 4);
        int r = r0 + rr;
        float4 v = (r < N) ? ((const float4*)(X + (size_t)r * NFEAT))[kk] : make_float4(0, 0, 0, 0);
        *(float4*)&xs[rr][kk * 4] = v;
    }
    __syncthreads();
    float s0 = 0.f, s1 = 0.f;
    for (int rr = wid * 16; rr < wid * 16 + 16; rr++) {
        int r = r0 + rr;
        if (r >= N) break;
        float acc = bcol;
#pragma unroll
        for (int k4 = 0; k4 < NFEAT; k4 += 4) {
            float4 xv = *(const float4*)&xs[rr][k4];
            acc += xv.x * w[k4] + xv.y * w[k4 + 1] + xv.z * w[k4 + 2] + xv.w * w[k4 + 3];
        }
        pre[r * D + lane] = acc;
        s0 += acc; s1 += acc * acc;
    }
    red[wid][0][lane] = s0; red[wid][1][lane] = s1;
    __syncthreads();
    if (tid < 64) {
        float a = red[0][0][lane] + red[1][0][lane] + red[2][0][lane] + red[3][0][lane];
        float b = red[0][1][lane] + red[1][1][lane] + red[2][1][lane] + red[3][1][lane];
        atomicAdd(&stats[lane], a);
        atomicAdd(&stats[64 + lane], b);
    }
}

// ---------------- BN + SiLU elementwise (stats finalized inline)
__global__ void k_bnsilu(const float* __restrict__ pre, const float* __restrict__ stats,
                         const float* __restrict__ g, const float* __restrict__ beta,
                         float* __restrict__ h, int N, float invn) {
    int idx = blockIdx.x * blockDim.x + threadIdx.x;
    int total = N * D / 4;
    if (idx >= total) return;
    int c0 = (idx * 4) & 63;
    float4 p = ((const float4*)pre)[idx];
    float pv[4] = {p.x, p.y, p.z, p.w}, o[4];
#pragma unroll
    for (int t = 0; t < 4; t++) {
        int c = c0 + t;
        float m = stats[c] * invn;
        float v = stats[64 + c] * invn - m * m;
        float sc = g[c] * rsqrtf(fmaxf(v, 0.f) + EPS);
        float sh = beta[c] - m * sc;
        float y = sc * pv[t] + sh;
        o[t] = y / (1.f + expf(-y));
    }
    ((float4*)h)[idx] = make_float4(o[0], o[1], o[2], o[3]);
}

// ---------------- pack edge weights for MFMA: WT[layer][c][k] = bf16(W_ef[k][c]), c=0..63 gate, 64..127 scr, k padded 41->64
__global__ void k_wpack(const float* __restrict__ convW, bf16* __restrict__ WT3) {
    int layer = blockIdx.x;
    const float* Wc = convW + (size_t)layer * 2 * 169 * 64;
    bf16* WT = WT3 + (size_t)layer * 128 * 64;
    for (int i = threadIdx.x; i < 128 * 64; i += blockDim.x) {
        int c = i >> 6, k = i & 63;
        float v = 0.f;
        if (k < EF) v = (c < 64) ? Wc[(128 + k) * 64 + c] : Wc[169 * 64 + (128 + k) * 64 + (c - 64)];
        WT[i] = f2b(v);
    }
}

// ---------------- node projections, packed output: SRCP[n][j] = (gate u16 | scr u16 << 16), DSTP likewise.
// Also zeroes upd for the subsequent apply pass.
#define NP_RPB 64
__global__ __launch_bounds__(256) void k_nodeproj(const float* __restrict__ h, const float* __restrict__ Wc,
                                                  unsigned* __restrict__ SRCP, unsigned* __restrict__ DSTP,
                                                  float* __restrict__ upd, int N) {
    __shared__ float hs[NP_RPB][D];   // 16 KB
    int tid = threadIdx.x;
    for (int i = blockIdx.x * 256 + tid; i < N * D / 4; i += gridDim.x * 256)
        ((float4*)upd)[i] = make_float4(0.f, 0.f, 0.f, 0.f);
    int j = tid & 63;
    int mat = tid >> 6;          // 0: src-gate 1: src-scr 2: dst-gate 3: dst-scr
    int jj = mat & 1;
    int roff = (mat >> 1) * 64;
    const float* Wb = Wc + ((size_t)jj * 169 + roff) * 64 + j;
    float w[D];
#pragma unroll
    for (int k = 0; k < D; k++) w[k] = Wb[k * 64];
    int r0 = blockIdx.x * NP_RPB;
    for (int i = tid; i < NP_RPB * D / 4; i += 256) {
        int rr = i >> 4, kk = (i & 15);
        int r = r0 + rr;
        float4 v = (r < N) ? ((const float4*)(h + (size_t)r * D))[kk] : make_float4(0, 0, 0, 0);
        *(float4*)&hs[rr][kk * 4] = v;
    }
    __syncthreads();
    unsigned short* out = (unsigned short*)((mat < 2) ? SRCP : DSTP);
    int rmax = min(NP_RPB, N - r0);
    for (int rr = 0; rr < rmax; rr++) {
        float acc = 0.f;
#pragma unroll
        for (int k4 = 0; k4 < D; k4 += 4) {
            float4 xv = *(const float4*)&hs[rr][k4];
            acc += xv.x * w[k4] + xv.y * w[k4 + 1] + xv.z * w[k4 + 2] + xv.w * w[k4 + 3];
        }
        out[(size_t)(r0 + rr) * 128 + j * 2 + jj] = f2b(acc);   // disjoint u16 halves across waves
    }
}

// ---------------- fused edge pass 1: MFMA ef@Wef + gather SRCP/DSTP + BN stats (on unrounded f32)
// + store packed bf16 preact PREP[E][64]. 64 edges/block, 16/wave. E % 64 == 0 (360000 = 5625*64).
__global__ __launch_bounds__(256) void k_efused(const float* __restrict__ ef, const bf16* __restrict__ WT,
                                                const int* __restrict__ src, const int* __restrict__ dst,
                                                const unsigned* __restrict__ SRCP, const unsigned* __restrict__ DSTP,
                                                unsigned* __restrict__ PREP, float* __restrict__ stats) {
    __shared__ float red[4][4][64];
    int tid = threadIdx.x, lane = tid & 63, wid = tid >> 6;
    int lr = lane & 15, lg = lane >> 4;
    int r0 = blockIdx.x * 64 + wid * 16;               // wave's 16 edges
    // A frags: lane holds A[lr][lg*8 + j] (k-blocked 16x16x32 layout); K padded 41->64 with zeros
    const float* arow = ef + (size_t)(r0 + lr) * EF;
    short8v a0, a1;
#pragma unroll
    for (int j = 0; j < 8; j++) a0[j] = (short)f2b(arow[lg * 8 + j]);          // k = 0..31, always valid
#pragma unroll
    for (int j = 0; j < 8; j++) {
        int k = 32 + lg * 8 + j;
        a1[j] = (k < EF) ? (short)f2b(arow[k]) : (short)0;
    }
    int sv = src[r0 + lr], dv = dst[r0 + lr];          // lanes 0-15 hold the wave's 16 src/dst indices
    float stg[4], sqg[4], sts_[4], sqs[4];
#pragma unroll
    for (int t = 0; t < 4; t++) { stg[t] = 0.f; sqg[t] = 0.f; sts_[t] = 0.f; sqs[t] = 0.f; }
#pragma unroll
    for (int t = 0; t < 4; t++) {                      // gate cols 16t..16t+15 paired with scr cols 64+16t..
        const bf16* wg = WT + (size_t)(16 * t + lr) * 64 + lg * 8;
        const bf16* wsc = WT + (size_t)(64 + 16 * t + lr) * 64 + lg * 8;
        float4v accg = {0.f, 0.f, 0.f, 0.f}, accs = {0.f, 0.f, 0.f, 0.f};
        accg = __builtin_amdgcn_mfma_f32_16x16x32_bf16(a0, *(const short8v*)wg, accg, 0, 0, 0);
        accg = __builtin_amdgcn_mfma_f32_16x16x32_bf16(a1, *(const short8v*)(wg + 32), accg, 0, 0, 0);
        accs = __builtin_amdgcn_mfma_f32_16x16x32_bf16(a0, *(const short8v*)wsc, accs, 0, 0, 0);
        accs = __builtin_amdgcn_mfma_f32_16x16x32_bf16(a1, *(const short8v*)(wsc + 32), accs, 0, 0, 0);
        int col = 16 * t + lr;
#pragma unroll
        for (int j = 0; j < 4; j++) {
            int row = lg * 4 + j;                      // D layout: row = (lane>>4)*4 + reg, col = lane&15
            int s = __shfl(sv, row), d = __shfl(dv, row);
            unsigned us = SRCP[(size_t)s * 64 + col];
            unsigned ud = DSTP[(size_t)d * 64 + col];
            float pg = accg[j] + lof(us) + lof(ud);
            float ps = accs[j] + hif(us) + hif(ud);
            stg[t] += pg; sqg[t] += pg * pg; sts_[t] += ps; sqs[t] += ps * ps;
            unsigned packed = (unsigned)f2b(pg) | ((unsigned)f2b(ps) << 16);
            __builtin_nontemporal_store(packed, &PREP[(size_t)(r0 + row) * 64 + col]);
        }
    }
    // stats: lane (lg,lr) col = 16t+lr; sum over the 4 lane-groups, then cross-wave, then atomics
#pragma unroll
    for (int t = 0; t < 4; t++) {
        float v0 = stg[t], v1 = sqg[t], v2 = sts_[t], v3 = sqs[t];
        v0 += __shfl_xor(v0, 16); v0 += __shfl_xor(v0, 32);
        v1 += __shfl_xor(v1, 16); v1 += __shfl_xor(v1, 32);
        v2 += __shfl_xor(v2, 16); v2 += __shfl_xor(v2, 32);
        v3 += __shfl_xor(v3, 16); v3 += __shfl_xor(v3, 32);
        if (lg == 0) {
            red[wid][0][16 * t + lr] = v0; red[wid][1][16 * t + lr] = v1;
            red[wid][2][16 * t + lr] = v2; red[wid][3][16 * t + lr] = v3;
        }
    }
    __syncthreads();
    if (tid < 64) {
#pragma unroll
        for (int q = 0; q < 4; q++) {
            float v = red[0][q][lane] + red[1][q][lane] + red[2][q][lane] + red[3][q][lane];
            atomicAdd(&stats[q * 64 + lane], v);
        }
    }
}

// ---------------- fused edge pass 2: stream PREP, BN-apply, sigmoid*softplus, atomic scatter to dst
__global__ __launch_bounds__(256) void k_eapply(const int* __restrict__ dst, const unsigned* __restrict__ PREP,
                                                const float* __restrict__ stats,
                                                const float* __restrict__ gg, const float* __restrict__ gb,
                                                const float* __restrict__ sg, const float* __restrict__ sb,
                                                float* __restrict__ upd, int E) {
    int tid = threadIdx.x, lane = tid & 63, wid = tid >> 6;
    float invE = 1.0f / (float)E;
    float m = stats[lane] * invE;
    float v = stats[64 + lane] * invE - m * m;
    float scg = gg[lane] * rsqrtf(fmaxf(v, 0.f) + EPS);
    float shg = gb[lane] - m * scg;
    m = stats[128 + lane] * invE;
    v = stats[192 + lane] * invE - m * m;
    float scs = sg[lane] * rsqrtf(fmaxf(v, 0.f) + EPS);
    float shs = sb[lane] - m * scs;
    int gw = blockIdx.x * 4 + wid;              // one 64-edge group per wave
    int e0 = gw * 64;
    if (e0 >= E) return;
    int dv = dst[e0 + lane];
    const unsigned* pp = PREP + (size_t)e0 * 64 + lane;
#pragma unroll 8
    for (int i = 0; i < 64; i++) {
        unsigned u = __builtin_nontemporal_load(&pp[(size_t)i * 64]);
        int d = __shfl(dv, i);
        float pg = lof(u), ps = hif(u);
        float yg = scg * pg + shg, ys = scs * ps + shs;
        float val = softplusf(ys) / (1.f + expf(-yg));
        atomicAdd(&upd[(size_t)d * 64 + lane], val);
    }
}

// ---------------- column stats of upd
__global__ __launch_bounds__(256) void k_colstats(const float* __restrict__ x, float* __restrict__ stats, int N) {
    int tid = threadIdx.x, lane = tid & 63, wid = tid >> 6;
    __shared__ float red[4][2][64];
    float s = 0, q = 0;
    int gw = blockIdx.x * 4 + wid, nw = gridDim.x * 4;
    for (int r = gw; r < N; r += nw) {
        float v = x[(size_t)r * D + lane];
        s += v; q += v * v;
    }
    red[wid][0][lane] = s; red[wid][1][lane] = q;
    __syncthreads();
    if (tid < 64) {
        float a = red[0][0][lane] + red[1][0][lane] + red[2][0][lane] + red[3][0][lane];
        float b = red[0][1][lane] + red[1][1][lane] + red[2][1][lane] + red[3][1][lane];
        atomicAdd(&stats[lane], a);
        atomicAdd(&stats[64 + lane], b);
    }
}

// ---------------- h = softplus(BN(upd) + h)
__global__ void k_updapply(const float* __restrict__ upd, const float* __restrict__ stats,
                           const float* __restrict__ g, const float* __restrict__ beta,
                           float* __restrict__ h, int N, float invn) {
    int idx = blockIdx.x * blockDim.x + threadIdx.x;
    int total = N * D / 4;
    if (idx >= total) return;
    int c0 = (idx * 4) & 63;
    float4 u = ((const float4*)upd)[idx];
    float4 hh = ((const float4*)h)[idx];
    float uv[4] = {u.x, u.y, u.z, u.w}, hv[4] = {hh.x, hh.y, hh.z, hh.w}, o[4];
#pragma unroll
    for (int t = 0; t < 4; t++) {
        int c = c0 + t;
        float m = stats[c] * invn, v = stats[64 + c] * invn - m * m;
        float sc = g[c] * rsqrtf(fmaxf(v, 0.f) + EPS);
        float sh = beta[c] - m * sc;
        o[t] = softplusf(sc * uv[t] + sh + hv[t]);
    }
    ((float4*)h)[idx] = make_float4(o[0], o[1], o[2], o[3]);
}

// ---------------- segment-sum pool (batch sorted): register accumulation, atomic per transition
__global__ __launch_bounds__(256) void k_pool(const float* __restrict__ h, const int* __restrict__ batch,
                                              float* __restrict__ pool, float* __restrict__ cnt, int N) {
    int tid = threadIdx.x, lane = tid & 63, wid = tid >> 6;
    int w = blockIdx.x * 4 + wid, nw = gridDim.x * 4;
    int chunk = (N + nw - 1) / nw;
    int r0 = w * chunk, r1 = min(N, r0 + chunk);
    if (r0 >= r1) return;
    int cur = batch[r0];
    float acc = 0.f, c = 0.f;
    for (int r = r0; r < r1; r++) {
        int b = batch[r];
        if (b != cur) {
            atomicAdd(&pool[(size_t)cur * D + lane], acc);
            if (lane == 0) atomicAdd(&cnt[cur], c);
            acc = 0.f; c = 0.f; cur = b;
        }
        acc += h[(size_t)r * D + lane];
        c += 1.f;
    }
    atomicAdd(&pool[(size_t)cur * D + lane], acc);
    if (lane == 0) atomicAdd(&cnt[cur], c);
}

// ---------------- fc: Y[g][j] = vt[g] . fcW[:,j] + fcb[j]; accumulate col stats
__global__ __launch_bounds__(128) void k_fc(const float* __restrict__ pool, const float* __restrict__ cnt,
                                            const float* __restrict__ fcW, const float* __restrict__ fcb,
                                            float* __restrict__ Y, float* __restrict__ ystats) {
    int g = blockIdx.x;
    int j = threadIdx.x;
    __shared__ float vt[FCW];
    {
        float s, c;
        if (j < 64) { s = pool[(size_t)g * D + j]; c = cnt[g]; }
        else { s = pool[4096 + (size_t)g * D + (j - 64)]; c = cnt[64 + g]; }
        vt[j] = s / fmaxf(c, 1.0f);
    }
    __syncthreads();
    float acc = fcb[j];
#pragma unroll
    for (int k4 = 0; k4 < FCW; k4 += 4) {
        float4 v = *(const float4*)&vt[k4];
        acc += v.x * fcW[(k4 + 0) * FCW + j] + v.y * fcW[(k4 + 1) * FCW + j] +
               v.z * fcW[(k4 + 2) * FCW + j] + v.w * fcW[(k4 + 3) * FCW + j];
    }
    Y[(size_t)g * FCW + j] = acc;
    atomicAdd(&ystats[j], acc);
    atomicAdd(&ystats[128 + j], acc * acc);
}

// ---------------- head: BN over 64 rows + SiLU + pred matvec → out[64] f32
__global__ __launch_bounds__(128) void k_head(const float* __restrict__ Y, const float* __restrict__ ystats,
                                              const float* __restrict__ fg, const float* __restrict__ fb,
                                              const float* __restrict__ pW, const float* __restrict__ pb,
                                              float* __restrict__ out) {
    int j = threadIdx.x;
    __shared__ float ys[NG][FCW + 1];
    __shared__ float pw[FCW];
    float invn = 1.0f / (float)NG;
    float m = ystats[j] * invn, v = ystats[128 + j] * invn - m * m;
    float sc = fg[j] * rsqrtf(fmaxf(v, 0.f) + EPS);
    float sh = fb[j] - m * sc;
    for (int g = 0; g < NG; g++) {
        float y = sc * Y[(size_t)g * FCW + j] + sh;
        ys[g][j] = y / (1.f + expf(-y));
    }
    pw[j] = pW[j];
    __syncthreads();
    if (j < NG) {
        float acc = pb[0];
        for (int k = 0; k < FCW; k++) acc += ys[j][k] * pw[k];
        out[j] = acc;
    }
}

// ---------------- workspace layout (bytes) — total 130,625,536 <= previously-granted 130,658,304
static const size_t OFF_EMBSTATS = 0;                    // [2][128] f32
static const size_t OFF_EDGESTATS = 1024;                // [6][256] f32
static const size_t OFF_UPDSTATS = 7168;                 // [6][128] f32
static const size_t OFF_POOL = 10240;                    // [2][4096] f32
static const size_t OFF_CNT = 43008;                     // [2][64] f32
static const size_t OFF_YSTATS = 43520;                  // [256] f32
static const size_t STATS_BYTES = 44544;
static const size_t OFF_H = 65536;                       // 30000*64*4
static const size_t OFF_SCRATCH = OFF_H + 7680000;       // emb preact f32; later WT3 (48K) + Y (32K)
static const size_t OFF_UPD = OFF_SCRATCH + 7680000;     // f32
static const size_t OFF_SRCP = OFF_UPD + 7680000;        // uint [30000][64] packed (gate|scr)
static const size_t OFF_DSTP = OFF_SRCP + 7680000;
static const size_t OFF_PREP = OFF_DSTP + 7680000;       // uint [360000][64] packed bf16 preacts

extern "C" void kernel_launch(void* const* d_in, const int* in_sizes, int n_in,
                              void* d_out, int out_size, void* d_ws, size_t ws_size,
                              hipStream_t stream) {
    char* ws = (char*)d_ws;
    hipMemsetAsync(d_ws, 0, STATS_BYTES, stream);

    float* h = (float*)(ws + OFF_H);
    float* scratch = (float*)(ws + OFF_SCRATCH);         // emb preact
    bf16* WT3 = (bf16*)(ws + OFF_SCRATCH);               // reused after bnsilu
    float* Y = (float*)(ws + OFF_SCRATCH + 49152);
    float* upd = (float*)(ws + OFF_UPD);
    unsigned* SRCP = (unsigned*)(ws + OFF_SRCP);
    unsigned* DSTP = (unsigned*)(ws + OFF_DSTP);
    unsigned* PREP = (unsigned*)(ws + OFF_PREP);

    for (int br = 0; br < 2; br++) {
        const float* vf = (const float*)d_in[br ? 2 : 0];
        const float* ef = (const float*)d_in[br ? 3 : 1];
        const int* srci = (const int*)d_in[br ? 7 : 4];
        const int* dsti = (const int*)d_in[br ? 8 : 5];
        const int* bat = (const int*)d_in[br ? 9 : 6];
        const float* embW = (const float*)d_in[br ? 14 : 10];
        const float* embB = (const float*)d_in[br ? 15 : 11];
        const float* embG = (const float*)d_in[br ? 16 : 12];
        const float* embBe = (const float*)d_in[br ? 17 : 13];
        const float* convW = (const float*)d_in[br ? 24 : 18];
        const float* convG = (const float*)d_in[br ? 26 : 20];
        const float* convBe = (const float*)d_in[br ? 27 : 21];
        const float* convNG = (const float*)d_in[br ? 28 : 22];
        const float* convNB = (const float*)d_in[br ? 29 : 23];

        float* embstats = (float*)(ws + OFF_EMBSTATS) + br * 128;
        float* poolp = (float*)(ws + OFF_POOL) + br * 4096;
        float* cntp = (float*)(ws + OFF_CNT) + br * 64;

        k_emb_mm<<<(NNODE + EMB_RPB - 1) / EMB_RPB, 256, 0, stream>>>(vf, embW, embB, scratch, embstats, NNODE);
        k_bnsilu<<<NNODE * D / 4 / 256, 256, 0, stream>>>(scratch, embstats, embG, embBe, h, NNODE, 1.0f / NNODE);
        k_wpack<<<3, 256, 0, stream>>>(convW, WT3);      // scratch now repurposed (bnsilu done)

        for (int i = 0; i < LAY; i++) {
            const float* Wc = convW + (size_t)i * 2 * 169 * 64;
            const bf16* WT = WT3 + (size_t)i * 128 * 64;
            float* estats = (float*)(ws + OFF_EDGESTATS) + (br * 3 + i) * 256;
            float* ustats = (float*)(ws + OFF_UPDSTATS) + (br * 3 + i) * 128;
            const float* gg = convG + (i * 2 + 0) * 64;
            const float* gb = convBe + (i * 2 + 0) * 64;
            const float* sg = convG + (i * 2 + 1) * 64;
            const float* sb = convBe + (i * 2 + 1) * 64;

            k_nodeproj<<<(NNODE + NP_RPB - 1) / NP_RPB, 256, 0, stream>>>(h, Wc, SRCP, DSTP, upd, NNODE);
            k_efused<<<NEDGE / 64, 256, 0, stream>>>(ef, WT, srci, dsti, SRCP, DSTP, PREP, estats);
            k_eapply<<<(NEDGE / 64 + 3) / 4, 256, 0, stream>>>(dsti, PREP, estats, gg, gb, sg, sb, upd, NEDGE);
            k_colstats<<<512, 256, 0, stream>>>(upd, ustats, NNODE);
            k_updapply<<<NNODE * D / 4 / 256, 256, 0, stream>>>(upd, ustats, convNG + i * 64, convNB + i * 64, h, NNODE, 1.0f / NNODE);
        }
        k_pool<<<128, 256, 0, stream>>>(h, bat, poolp, cntp, NNODE);
    }

    float* poolall = (float*)(ws + OFF_POOL);
    float* cntall = (float*)(ws + OFF_CNT);
    float* ystats = (float*)(ws + OFF_YSTATS);
    k_fc<<<64, 128, 0, stream>>>(poolall, cntall, (const float*)d_in[30], (const float*)d_in[31], Y, ystats);
    k_head<<<1, 128, 0, stream>>>(Y, ystats, (const float*)d_in[32], (const float*)d_in[33],
                                  (const float*)d_in[34], (const float*)d_in[35], (float*)d_out);
}